// Round 7
// baseline (341.631 us; speedup 1.0000x reference)
//
#include <hip/hip_runtime.h>
#include <hip/hip_bf16.h>

// Round 10: recovery from round-9's cvt_pk failure (absmax 3.86 -- O(1)
// error signature = packed lo/hi order mismatch, not rounding; asm
// primitive shelved, not re-gambled blind). GEMM = round-3 structure
// (best measured). Flash = round-5 scalar P-store path, with the P
// quantizer cheapened from 4-instr RNE f2bf to 2-instr round-half-up
// ((u+0x8000)>>16): P>0, differs from RNE only on exact ties (~2^-16
// rate, 1 ulp, num/denom consistent) -- cuts ~128 VALU instr/kt/thread
// from flash's bottleneck pipe (VALUBusy 48% > MfmaUtil 28%).

using bf16 = __hip_bfloat16;
typedef __attribute__((ext_vector_type(8))) short short8;
typedef __attribute__((ext_vector_type(4))) short short4v;
typedef _Float16 half8 __attribute__((ext_vector_type(8)));
typedef __attribute__((ext_vector_type(4))) float floatx4;

#define E_DIM 1024
#define H_NUM 16
#define D_DIM 64
#define B_NUM 4
#define S_LEN 2048
#define M_TOT 8192  // B*S

__device__ __forceinline__ void async_ld16(const void* g, void* l) {
  __builtin_amdgcn_global_load_lds(
      (const __attribute__((address_space(1))) unsigned int*)g,
      (__attribute__((address_space(3))) unsigned int*)l, 16, 0, 0);
}

// fp32 -> bf16 round-to-nearest-even (explicit; ROCm cast rounding is
// version-dependent). Inputs finite.
__device__ __forceinline__ short f2bf(float x) {
  unsigned u = __builtin_bit_cast(unsigned, x);
  u += 0x7FFFu + ((u >> 16) & 1u);
  return (short)(u >> 16);
}

// 4 weight matrices in one dispatch. grid (E*E/4/256, 4).
__global__ void cvt_w4(const float* __restrict__ a, const float* __restrict__ b,
                       const float* __restrict__ c, const float* __restrict__ d,
                       short* __restrict__ oa, short* __restrict__ ob,
                       short* __restrict__ oc, short* __restrict__ od) {
  const int z = blockIdx.y;
  const float* src = z == 0 ? a : z == 1 ? b : z == 2 ? c : d;
  short* dst = z == 0 ? oa : z == 1 ? ob : z == 2 ? oc : od;
  const int i = blockIdx.x * blockDim.x + threadIdx.x;
  float4 v = ((const float4*)src)[i];
  short4v o;
  o[0] = f2bf(v.x); o[1] = f2bf(v.y); o[2] = f2bf(v.z); o[3] = f2bf(v.w);
  ((short4v*)dst)[i] = o;
}

// Q,K,V activations in one dispatch. grid (M*E/4/256, 3).
__global__ void cvt_a3(const float* __restrict__ a, const float* __restrict__ b,
                       const float* __restrict__ c, short* __restrict__ oa,
                       short* __restrict__ ob, short* __restrict__ oc) {
  const int z = blockIdx.y;
  const float* src = z == 0 ? a : z == 1 ? b : c;
  short* dst = z == 0 ? oa : z == 1 ? ob : oc;
  const int i = blockIdx.x * blockDim.x + threadIdx.x;
  float4 v = ((const float4*)src)[i];
  short4v o;
  o[0] = f2bf(v.x); o[1] = f2bf(v.y); o[2] = f2bf(v.z); o[3] = f2bf(v.w);
  ((short4v*)dst)[i] = o;
}

// C = A @ W^T, A bf16 [M,K], W bf16 [N,K], both via global_load_lds with
// XOR-swizzled LDS (BK=64).  (Round-3 version -- best measured.)
// MODE 0: QKV batch, grid (8,64,3). z=0/1 -> f16 [M,N]; z=2 -> bf16 [N,M]
//         via LDS-restaged coalesced short8 stores.
// MODE 2: single, grid (8,64,1), f32 [M,N] + bias.
template <int MODE>
__global__ __launch_bounds__(256, 3) void gemm_k(
    const short* __restrict__ A0, const short* __restrict__ A1,
    const short* __restrict__ A2, const short* __restrict__ W0,
    const short* __restrict__ W1, const short* __restrict__ W2,
    void* __restrict__ C0, void* __restrict__ C1p, void* __restrict__ C2p,
    const float* __restrict__ bias) {
  __shared__ __align__(16) char smem[MODE == 0 ? 34816 : 32768];
  short* As = (short*)smem;            // bf16 [128][64] swizzled
  short* Ws = (short*)(smem + 16384);  // bf16 [128][64] swizzled
  short* Cs = (short*)smem;            // bf16 [128][136] (z==2 epilogue only)

  const int M = M_TOT, N = E_DIM, K = E_DIM;
  const int tid = threadIdx.x;
  const int wave = tid >> 6;
  const int lane = tid & 63;
  const int quad = lane >> 4;
  const int l16 = lane & 15;
  const int wr = wave >> 1, wc = wave & 1;

  const int z = (MODE == 0) ? blockIdx.z : 0;
  const short* A = (MODE == 0) ? (z == 0 ? A0 : z == 1 ? A1 : A2) : A0;
  const short* W = (MODE == 0) ? (z == 0 ? W0 : z == 1 ? W1 : W2) : W0;

  const int nBase = (blockIdx.y & 7) * 128;
  const int mBase = (blockIdx.x * 8 + (blockIdx.y >> 3)) * 128;

  // Staging source swizzle: dest slot s=lane&7 of row r holds global
  // col-group s ^ (r&7); read side applies same XOR (both-sides rule).
  const int sRow = lane >> 3;
  const int sSwz = ((lane & 7) ^ sRow) * 8;
  const int rdSwz0 = ((0 * 4 + quad) ^ (l16 & 7)) * 8;
  const int rdSwz1 = ((1 * 4 + quad) ^ (l16 & 7)) * 8;

  floatx4 acc[4][4] = {};

  for (int kb = 0; kb < K; kb += 64) {
    __syncthreads();
#pragma unroll
    for (int t = 0; t < 4; t++) {
      const int r0 = wave * 32 + t * 8;
      async_ld16(&W[(size_t)(nBase + r0 + sRow) * K + kb + sSwz], &Ws[r0 * 64]);
      async_ld16(&A[(size_t)(mBase + r0 + sRow) * K + kb + sSwz], &As[r0 * 64]);
    }
    __syncthreads();
#pragma unroll
    for (int ks = 0; ks < 2; ks++) {
      const int rs = ks ? rdSwz1 : rdSwz0;
      short8 af[4], wf[4];
#pragma unroll
      for (int i = 0; i < 4; i++)
        af[i] = *(const short8*)&As[(wr * 64 + i * 16 + l16) * 64 + rs];
#pragma unroll
      for (int j = 0; j < 4; j++)
        wf[j] = *(const short8*)&Ws[(wc * 64 + j * 16 + l16) * 64 + rs];
#pragma unroll
      for (int i = 0; i < 4; i++)
#pragma unroll
        for (int j = 0; j < 4; j++)
          acc[i][j] = __builtin_amdgcn_mfma_f32_16x16x32_bf16(af[i], wf[j], acc[i][j], 0, 0, 0);
    }
  }

  if (MODE == 2) {
#pragma unroll
    for (int i = 0; i < 4; i++) {
      const int row0 = mBase + wr * 64 + i * 16 + quad * 4;
#pragma unroll
      for (int j = 0; j < 4; j++) {
        const int col = nBase + wc * 64 + j * 16 + l16;
        const float bv = bias[col];
#pragma unroll
        for (int r = 0; r < 4; r++)
          ((float*)C0)[(size_t)(row0 + r) * N + col] = acc[i][j][r] + bv;
      }
    }
  } else if (z != 2) {
    _Float16* C = (_Float16*)(z == 0 ? C0 : C1p);
#pragma unroll
    for (int i = 0; i < 4; i++) {
      const int row0 = mBase + wr * 64 + i * 16 + quad * 4;
#pragma unroll
      for (int j = 0; j < 4; j++) {
        const int col = nBase + wc * 64 + j * 16 + l16;
#pragma unroll
        for (int r = 0; r < 4; r++)
          C[(size_t)(row0 + r) * N + col] = (_Float16)acc[i][j][r];
      }
    }
  } else {
    // bf16 [N,M]: restage through LDS, store coalesced short8 rows of C^T.
    __syncthreads();  // all LDS fragment reads done before Cs overwrites
#pragma unroll
    for (int i = 0; i < 4; i++) {
      const int rl = wr * 64 + i * 16 + quad * 4;
#pragma unroll
      for (int j = 0; j < 4; j++) {
        const int cl = wc * 64 + j * 16 + l16;
#pragma unroll
        for (int r = 0; r < 4; r++)
          Cs[cl * 136 + rl + r] = f2bf(acc[i][j][r]);
      }
    }
    __syncthreads();
    short* C = (short*)C2p;
#pragma unroll
    for (int p = 0; p < 8; p++) {
      const int id = p * 256 + tid;
      const int nl = id >> 4, mc = (id & 15) * 8;
      *(short8*)&C[(size_t)(nBase + nl) * M + mBase + mc] =
          *(const short8*)&Cs[nl * 136 + mc];
    }
  }
}

// Flash attention v2. q,k: f16 [M,E]; vt: bf16 [E,M]; o: bf16 [M,E].
// Softmax over UNSCALED scores (reference bug preserved), shift-by-40;
// rowsum via ones-MFMA; T1 swizzle + T5 setprio.
// Round 10: P quantizer = round-half-up (2 VALU), scalar store path.
__global__ __launch_bounds__(256, 3) void flash_attn(
    const _Float16* __restrict__ q, const _Float16* __restrict__ k,
    const short* __restrict__ vt, short* __restrict__ o) {
  __shared__ __align__(16) char smem[51200];
  short* Vts = (short*)smem;                    // bf16 [64][128] swizzled, 16KB
  _Float16* Ks = (_Float16*)(smem + 16384);     // f16 [128][64] swizzled, 16KB
  short* PsW = (short*)(smem + 16384 + (threadIdx.x >> 6) * 8704);

  const int tid = threadIdx.x;
  const int wave = tid >> 6;
  const int lane = tid & 63;
  const int quad = lane >> 4;
  const int l16 = lane & 15;

  int qRow0, h, b;
  {
    int l = blockIdx.x + ((blockIdx.y + (blockIdx.z << 4)) << 4);
    l = (l & 7) * 128 + (l >> 3);               // nwg=1024, bijective
    qRow0 = (l & 15) * 128;
    h = (l >> 4) & 15;
    b = l >> 8;
  }

  const _Float16* qp = q + (size_t)(b * S_LEN + qRow0) * E_DIM + h * D_DIM;
  const _Float16* kp = k + (size_t)(b * S_LEN) * E_DIM + h * D_DIM;
  const short* vtp = vt + (size_t)(h * D_DIM) * M_TOT + b * S_LEN;
  short* op = o + (size_t)(b * S_LEN + qRow0) * E_DIM + h * D_DIM;

  half8 qf[2][2];
#pragma unroll
  for (int i = 0; i < 2; i++)
#pragma unroll
    for (int ks = 0; ks < 2; ks++)
      qf[i][ks] = *(const half8*)&qp[(size_t)(wave * 32 + i * 16 + l16) * E_DIM + ks * 32 + quad * 8];

  short8 ones;
#pragma unroll
  for (int j = 0; j < 8; j++) ones[j] = (l16 == 0) ? (short)0x3F80 : (short)0;

  floatx4 oacc[2][4] = {};
  floatx4 oaccL[2] = {};

  const int kRow = lane >> 3, kChk = lane & 7;
  const int vRow = lane >> 4, vChk = lane & 15;

  for (int kt = 0; kt < 16; kt++) {
    __syncthreads();  // (A) prior tile's Ps/Vts reads complete
#pragma unroll
    for (int t = 0; t < 4; t++) {
      const int r0 = wave * 32 + t * 8;
      const int gcol = (kChk ^ kRow) * 8;
      async_ld16(&kp[(size_t)(kt * 128 + r0 + kRow) * E_DIM + gcol], &Ks[r0 * 64]);
    }
#pragma unroll
    for (int t = 0; t < 4; t++) {
      const int r0 = wave * 16 + t * 4;
      const int row = r0 + vRow;
      const int gcol = (vChk ^ (row & 15)) * 8;
      async_ld16(&vtp[(size_t)row * M_TOT + kt * 128 + gcol], &Vts[r0 * 128]);
    }
    __syncthreads();  // (B) tiles staged

    floatx4 sc[2][8] = {};
    __builtin_amdgcn_s_setprio(1);
#pragma unroll
    for (int jt = 0; jt < 8; jt++) {
#pragma unroll
      for (int ks = 0; ks < 2; ks++) {
        const int scol = ((ks * 4 + quad) ^ (l16 & 7)) * 8;
        half8 kf = *(const half8*)&Ks[(jt * 16 + l16) * 64 + scol];
        sc[0][jt] = __builtin_amdgcn_mfma_f32_16x16x32_f16(qf[0][ks], kf, sc[0][jt], 0, 0, 0);
        sc[1][jt] = __builtin_amdgcn_mfma_f32_16x16x32_f16(qf[1][ks], kf, sc[1][jt], 0, 0, 0);
      }
    }
    __builtin_amdgcn_s_setprio(0);
    __syncthreads();  // (C) all Ks reads done before Ps overwrites them

    // p = exp(s - 40); softmax is shift-invariant, 40 keeps exp in range.
    // Quantize p (always > 0) to bf16 with round-half-up: (u+0x8000)>>16.
    // Differs from RNE only on exact ties (1 ulp, ~2^-16 rate); the same
    // quantized P feeds numerator and denominator, so the effect cancels.
#pragma unroll
    for (int i = 0; i < 2; i++)
#pragma unroll
      for (int r = 0; r < 4; r++) {
        const int prow = i * 16 + quad * 4 + r;
#pragma unroll
        for (int jt = 0; jt < 8; jt++) {
          const float p = __expf(sc[i][jt][r] - 40.0f);
          const unsigned u = __builtin_bit_cast(unsigned, p);
          PsW[prow * 136 + jt * 16 + l16] = (short)((u + 0x8000u) >> 16);
        }
      }

    __builtin_amdgcn_s_setprio(1);
#pragma unroll
    for (int ks = 0; ks < 4; ks++) {
      short8 pf[2];
#pragma unroll
      for (int i = 0; i < 2; i++)
        pf[i] = *(const short8*)&PsW[(i * 16 + l16) * 136 + ks * 32 + quad * 8];
#pragma unroll
      for (int dt = 0; dt < 4; dt++) {
        const int scol = ((ks * 4 + quad) ^ l16) * 8;
        short8 vf = *(const short8*)&Vts[(dt * 16 + l16) * 128 + scol];
        oacc[0][dt] = __builtin_amdgcn_mfma_f32_16x16x32_bf16(pf[0], vf, oacc[0][dt], 0, 0, 0);
        oacc[1][dt] = __builtin_amdgcn_mfma_f32_16x16x32_bf16(pf[1], vf, oacc[1][dt], 0, 0, 0);
      }
      oaccL[0] = __builtin_amdgcn_mfma_f32_16x16x32_bf16(pf[0], ones, oaccL[0], 0, 0, 0);
      oaccL[1] = __builtin_amdgcn_mfma_f32_16x16x32_bf16(pf[1], ones, oaccL[1], 0, 0, 0);
    }
    __builtin_amdgcn_s_setprio(0);
  }

#pragma unroll
  for (int i = 0; i < 2; i++)
#pragma unroll
    for (int r = 0; r < 4; r++) {
      const float ls = __shfl(oaccL[i][r], lane & 48, 64);
      const float inv = 1.0f / ls;
      const int row = wave * 32 + i * 16 + quad * 4 + r;
#pragma unroll
      for (int dt = 0; dt < 4; dt++)
        op[(size_t)row * E_DIM + dt * 16 + l16] = f2bf(oacc[i][dt][r] * inv);
    }
}

extern "C" void kernel_launch(void* const* d_in, const int* in_sizes, int n_in,
                              void* d_out, int out_size, void* d_ws, size_t ws_size,
                              hipStream_t stream) {
  const float* Q  = (const float*)d_in[0];
  const float* K  = (const float*)d_in[1];
  const float* V  = (const float*)d_in[2];
  const float* Wq = (const float*)d_in[3];
  const float* Wk = (const float*)d_in[4];
  const float* Wv = (const float*)d_in[5];
  const float* Wo = (const float*)d_in[6];
  const float* bo = (const float*)d_in[7];
  float* out = (float*)d_out;

  char* ws = (char*)d_ws;
  const size_t wsz = (size_t)E_DIM * E_DIM * 2;   // 2MB per bf16 weight
  short* wqb = (short*)ws; ws += wsz;
  short* wkb = (short*)ws; ws += wsz;
  short* wvb = (short*)ws; ws += wsz;
  short* wob = (short*)ws; ws += wsz;
  const size_t asz = (size_t)M_TOT * E_DIM * 2;   // 16MB per activation
  _Float16* qw = (_Float16*)ws; ws += asz;
  _Float16* kw = (_Float16*)ws; ws += asz;
  short* vtw = (short*)ws;      ws += asz;        // bf16 [E, M]
  short* aw  = (short*)ws;      ws += asz;        // bf16 [M, E]
  // bf16 activation scratch, dead before final consumers: qbf -> aw (flash
  // writes aw later); kbf, vbf -> d_out (final GEMM writes out last).
  short* qbf = aw;
  short* kbf = (short*)d_out;
  short* vbf = (short*)d_out + (size_t)M_TOT * E_DIM;

  dim3 blk(256);
  cvt_w4<<<dim3(E_DIM * E_DIM / 4 / 256, 4), blk, 0, stream>>>(
      Wq, Wk, Wv, Wo, wqb, wkb, wvb, wob);
  cvt_a3<<<dim3(M_TOT * E_DIM / 4 / 256, 3), blk, 0, stream>>>(
      Q, K, V, qbf, kbf, vbf);

  gemm_k<0><<<dim3(8, 64, 3), blk, 0, stream>>>(
      qbf, kbf, vbf, wqb, wkb, wvb, qw, kw, vtw, nullptr);
  flash_attn<<<dim3(S_LEN / 128, H_NUM, B_NUM), blk, 0, stream>>>(qw, kw, vtw, aw);
  gemm_k<2><<<dim3(8, 64, 1), blk, 0, stream>>>(
      aw, nullptr, nullptr, wob, nullptr, nullptr, out, nullptr, nullptr, bo);
}

// Round 8
// 337.484 us; speedup vs baseline: 1.0123x; 1.0123x over previous
//
#include <hip/hip_runtime.h>
#include <hip/hip_bf16.h>

// Round 11: flash residency fix. Evidence: Occupancy 24.9% == exact average
// of a 2-round schedule (1024 blocks at 3/CU = 768 resident + 256 tail) ->
// wall = 2*tau with pipes mostly idle (VALU 42%, MFMA 28%). KVBLK 128->64
// cuts LDS 51200->26624 (Vts 8K + Ks 8K, Ps[32][72]/wave aliased over Ks)
// -> 5-6 blocks/CU -> all 1024 blocks co-resident, one round; cross-block
// overlap fills stalls (m114: VALU+MFMA = max not sum). Accumulation order
// bitwise identical (same ascending kv-chunk sequence). GEMMs/cvts
// byte-identical to round 10 (passed) -- single-variable round.

using bf16 = __hip_bfloat16;
typedef __attribute__((ext_vector_type(8))) short short8;
typedef __attribute__((ext_vector_type(4))) short short4v;
typedef _Float16 half8 __attribute__((ext_vector_type(8)));
typedef __attribute__((ext_vector_type(4))) float floatx4;

#define E_DIM 1024
#define H_NUM 16
#define D_DIM 64
#define B_NUM 4
#define S_LEN 2048
#define M_TOT 8192  // B*S

__device__ __forceinline__ void async_ld16(const void* g, void* l) {
  __builtin_amdgcn_global_load_lds(
      (const __attribute__((address_space(1))) unsigned int*)g,
      (__attribute__((address_space(3))) unsigned int*)l, 16, 0, 0);
}

// fp32 -> bf16 round-to-nearest-even (explicit; ROCm cast rounding is
// version-dependent). Inputs finite.
__device__ __forceinline__ short f2bf(float x) {
  unsigned u = __builtin_bit_cast(unsigned, x);
  u += 0x7FFFu + ((u >> 16) & 1u);
  return (short)(u >> 16);
}

// 4 weight matrices in one dispatch. grid (E*E/4/256, 4).
__global__ void cvt_w4(const float* __restrict__ a, const float* __restrict__ b,
                       const float* __restrict__ c, const float* __restrict__ d,
                       short* __restrict__ oa, short* __restrict__ ob,
                       short* __restrict__ oc, short* __restrict__ od) {
  const int z = blockIdx.y;
  const float* src = z == 0 ? a : z == 1 ? b : z == 2 ? c : d;
  short* dst = z == 0 ? oa : z == 1 ? ob : z == 2 ? oc : od;
  const int i = blockIdx.x * blockDim.x + threadIdx.x;
  float4 v = ((const float4*)src)[i];
  short4v o;
  o[0] = f2bf(v.x); o[1] = f2bf(v.y); o[2] = f2bf(v.z); o[3] = f2bf(v.w);
  ((short4v*)dst)[i] = o;
}

// Q,K,V activations in one dispatch. grid (M*E/4/256, 3).
__global__ void cvt_a3(const float* __restrict__ a, const float* __restrict__ b,
                       const float* __restrict__ c, short* __restrict__ oa,
                       short* __restrict__ ob, short* __restrict__ oc) {
  const int z = blockIdx.y;
  const float* src = z == 0 ? a : z == 1 ? b : c;
  short* dst = z == 0 ? oa : z == 1 ? ob : oc;
  const int i = blockIdx.x * blockDim.x + threadIdx.x;
  float4 v = ((const float4*)src)[i];
  short4v o;
  o[0] = f2bf(v.x); o[1] = f2bf(v.y); o[2] = f2bf(v.z); o[3] = f2bf(v.w);
  ((short4v*)dst)[i] = o;
}

// C = A @ W^T, A bf16 [M,K], W bf16 [N,K], both via global_load_lds with
// XOR-swizzled LDS (BK=64).  (Round-3 version -- best measured.)
// MODE 0: QKV batch, grid (8,64,3). z=0/1 -> f16 [M,N]; z=2 -> bf16 [N,M]
//         via LDS-restaged coalesced short8 stores.
// MODE 2: single, grid (8,64,1), f32 [M,N] + bias.
template <int MODE>
__global__ __launch_bounds__(256, 3) void gemm_k(
    const short* __restrict__ A0, const short* __restrict__ A1,
    const short* __restrict__ A2, const short* __restrict__ W0,
    const short* __restrict__ W1, const short* __restrict__ W2,
    void* __restrict__ C0, void* __restrict__ C1p, void* __restrict__ C2p,
    const float* __restrict__ bias) {
  __shared__ __align__(16) char smem[MODE == 0 ? 34816 : 32768];
  short* As = (short*)smem;            // bf16 [128][64] swizzled
  short* Ws = (short*)(smem + 16384);  // bf16 [128][64] swizzled
  short* Cs = (short*)smem;            // bf16 [128][136] (z==2 epilogue only)

  const int M = M_TOT, N = E_DIM, K = E_DIM;
  const int tid = threadIdx.x;
  const int wave = tid >> 6;
  const int lane = tid & 63;
  const int quad = lane >> 4;
  const int l16 = lane & 15;
  const int wr = wave >> 1, wc = wave & 1;

  const int z = (MODE == 0) ? blockIdx.z : 0;
  const short* A = (MODE == 0) ? (z == 0 ? A0 : z == 1 ? A1 : A2) : A0;
  const short* W = (MODE == 0) ? (z == 0 ? W0 : z == 1 ? W1 : W2) : W0;

  const int nBase = (blockIdx.y & 7) * 128;
  const int mBase = (blockIdx.x * 8 + (blockIdx.y >> 3)) * 128;

  // Staging source swizzle: dest slot s=lane&7 of row r holds global
  // col-group s ^ (r&7); read side applies same XOR (both-sides rule).
  const int sRow = lane >> 3;
  const int sSwz = ((lane & 7) ^ sRow) * 8;
  const int rdSwz0 = ((0 * 4 + quad) ^ (l16 & 7)) * 8;
  const int rdSwz1 = ((1 * 4 + quad) ^ (l16 & 7)) * 8;

  floatx4 acc[4][4] = {};

  for (int kb = 0; kb < K; kb += 64) {
    __syncthreads();
#pragma unroll
    for (int t = 0; t < 4; t++) {
      const int r0 = wave * 32 + t * 8;
      async_ld16(&W[(size_t)(nBase + r0 + sRow) * K + kb + sSwz], &Ws[r0 * 64]);
      async_ld16(&A[(size_t)(mBase + r0 + sRow) * K + kb + sSwz], &As[r0 * 64]);
    }
    __syncthreads();
#pragma unroll
    for (int ks = 0; ks < 2; ks++) {
      const int rs = ks ? rdSwz1 : rdSwz0;
      short8 af[4], wf[4];
#pragma unroll
      for (int i = 0; i < 4; i++)
        af[i] = *(const short8*)&As[(wr * 64 + i * 16 + l16) * 64 + rs];
#pragma unroll
      for (int j = 0; j < 4; j++)
        wf[j] = *(const short8*)&Ws[(wc * 64 + j * 16 + l16) * 64 + rs];
#pragma unroll
      for (int i = 0; i < 4; i++)
#pragma unroll
        for (int j = 0; j < 4; j++)
          acc[i][j] = __builtin_amdgcn_mfma_f32_16x16x32_bf16(af[i], wf[j], acc[i][j], 0, 0, 0);
    }
  }

  if (MODE == 2) {
#pragma unroll
    for (int i = 0; i < 4; i++) {
      const int row0 = mBase + wr * 64 + i * 16 + quad * 4;
#pragma unroll
      for (int j = 0; j < 4; j++) {
        const int col = nBase + wc * 64 + j * 16 + l16;
        const float bv = bias[col];
#pragma unroll
        for (int r = 0; r < 4; r++)
          ((float*)C0)[(size_t)(row0 + r) * N + col] = acc[i][j][r] + bv;
      }
    }
  } else if (z != 2) {
    _Float16* C = (_Float16*)(z == 0 ? C0 : C1p);
#pragma unroll
    for (int i = 0; i < 4; i++) {
      const int row0 = mBase + wr * 64 + i * 16 + quad * 4;
#pragma unroll
      for (int j = 0; j < 4; j++) {
        const int col = nBase + wc * 64 + j * 16 + l16;
#pragma unroll
        for (int r = 0; r < 4; r++)
          C[(size_t)(row0 + r) * N + col] = (_Float16)acc[i][j][r];
      }
    }
  } else {
    // bf16 [N,M]: restage through LDS, store coalesced short8 rows of C^T.
    __syncthreads();  // all LDS fragment reads done before Cs overwrites
#pragma unroll
    for (int i = 0; i < 4; i++) {
      const int rl = wr * 64 + i * 16 + quad * 4;
#pragma unroll
      for (int j = 0; j < 4; j++) {
        const int cl = wc * 64 + j * 16 + l16;
#pragma unroll
        for (int r = 0; r < 4; r++)
          Cs[cl * 136 + rl + r] = f2bf(acc[i][j][r]);
      }
    }
    __syncthreads();
    short* C = (short*)C2p;
#pragma unroll
    for (int p = 0; p < 8; p++) {
      const int id = p * 256 + tid;
      const int nl = id >> 4, mc = (id & 15) * 8;
      *(short8*)&C[(size_t)(nBase + nl) * M + mBase + mc] =
          *(const short8*)&Cs[nl * 136 + mc];
    }
  }
}

// Flash attention v2. q,k: f16 [M,E]; vt: bf16 [E,M]; o: bf16 [M,E].
// Softmax over UNSCALED scores (reference bug preserved), shift-by-40;
// rowsum via ones-MFMA; T1 swizzle + T5 setprio.
// Round 11: KVBLK=64 -> LDS 26624 B -> 5-6 blocks/CU, all 1024 co-resident.
__global__ __launch_bounds__(256, 4) void flash_attn(
    const _Float16* __restrict__ q, const _Float16* __restrict__ k,
    const short* __restrict__ vt, short* __restrict__ o) {
  __shared__ __align__(16) char smem[26624];
  short* Vts = (short*)smem;                    // bf16 [64 d][64 kv] swz, 8KB
  _Float16* Ks = (_Float16*)(smem + 8192);      // f16 [64 kv][64 d] swz, 8KB
  // Ps aliases Ks (Ks dead after QK): per-wave bf16 [32][72], 4x4608B
  short* PsW = (short*)(smem + 8192 + (threadIdx.x >> 6) * 4608);

  const int tid = threadIdx.x;
  const int wave = tid >> 6;
  const int lane = tid & 63;
  const int quad = lane >> 4;
  const int l16 = lane & 15;

  int qRow0, h, b;
  {
    int l = blockIdx.x + ((blockIdx.y + (blockIdx.z << 4)) << 4);
    l = (l & 7) * 128 + (l >> 3);               // nwg=1024, bijective
    qRow0 = (l & 15) * 128;
    h = (l >> 4) & 15;
    b = l >> 8;
  }

  const _Float16* qp = q + (size_t)(b * S_LEN + qRow0) * E_DIM + h * D_DIM;
  const _Float16* kp = k + (size_t)(b * S_LEN) * E_DIM + h * D_DIM;
  const short* vtp = vt + (size_t)(h * D_DIM) * M_TOT + b * S_LEN;
  short* op = o + (size_t)(b * S_LEN + qRow0) * E_DIM + h * D_DIM;

  half8 qf[2][2];
#pragma unroll
  for (int i = 0; i < 2; i++)
#pragma unroll
    for (int ks = 0; ks < 2; ks++)
      qf[i][ks] = *(const half8*)&qp[(size_t)(wave * 32 + i * 16 + l16) * E_DIM + ks * 32 + quad * 8];

  short8 ones;
#pragma unroll
  for (int j = 0; j < 8; j++) ones[j] = (l16 == 0) ? (short)0x3F80 : (short)0;

  floatx4 oacc[2][4] = {};
  floatx4 oaccL[2] = {};

  // Staging: 128-B rows (8 x 16B chunks); lane L -> row r0 + (L>>3),
  // slot L&7; slot s of row r holds global chunk s ^ (r&7) (r0 % 8 == 0).
  const int sRow = lane >> 3;
  const int sSwz = ((lane & 7) ^ sRow) * 8;

  for (int kt = 0; kt < 32; kt++) {
    __syncthreads();  // (A) prior tile's Ps/Vts reads complete
#pragma unroll
    for (int t = 0; t < 2; t++) {
      const int r0 = wave * 16 + t * 8;
      async_ld16(&kp[(size_t)(kt * 64 + r0 + sRow) * E_DIM + sSwz], &Ks[r0 * 64]);
    }
#pragma unroll
    for (int t = 0; t < 2; t++) {
      const int r0 = wave * 16 + t * 8;
      async_ld16(&vtp[(size_t)(r0 + sRow) * M_TOT + kt * 64 + sSwz], &Vts[r0 * 64]);
    }
    __syncthreads();  // (B) tiles staged

    floatx4 sc[2][4] = {};
    __builtin_amdgcn_s_setprio(1);
#pragma unroll
    for (int jt = 0; jt < 4; jt++) {
#pragma unroll
      for (int ks = 0; ks < 2; ks++) {
        const int scol = ((ks * 4 + quad) ^ (l16 & 7)) * 8;
        half8 kf = *(const half8*)&Ks[(jt * 16 + l16) * 64 + scol];
        sc[0][jt] = __builtin_amdgcn_mfma_f32_16x16x32_f16(qf[0][ks], kf, sc[0][jt], 0, 0, 0);
        sc[1][jt] = __builtin_amdgcn_mfma_f32_16x16x32_f16(qf[1][ks], kf, sc[1][jt], 0, 0, 0);
      }
    }
    __builtin_amdgcn_s_setprio(0);
    __syncthreads();  // (C) all Ks reads done before Ps overwrites them

    // p = exp(s - 40); softmax is shift-invariant, 40 keeps exp in range.
    // Quantize p (> 0) to bf16 with round-half-up: (u+0x8000)>>16 (differs
    // from RNE only on exact ties; num/denom consistent).
#pragma unroll
    for (int i = 0; i < 2; i++)
#pragma unroll
      for (int r = 0; r < 4; r++) {
        const int prow = i * 16 + quad * 4 + r;
#pragma unroll
        for (int jt = 0; jt < 4; jt++) {
          const float p = __expf(sc[i][jt][r] - 40.0f);
          const unsigned u = __builtin_bit_cast(unsigned, p);
          PsW[prow * 72 + jt * 16 + l16] = (short)((u + 0x8000u) >> 16);
        }
      }

    __builtin_amdgcn_s_setprio(1);
#pragma unroll
    for (int ks = 0; ks < 2; ks++) {
      short8 pf[2];
#pragma unroll
      for (int i = 0; i < 2; i++)
        pf[i] = *(const short8*)&PsW[(i * 16 + l16) * 72 + ks * 32 + quad * 8];
#pragma unroll
      for (int dt = 0; dt < 4; dt++) {
        const int scol = ((ks * 4 + quad) ^ (l16 & 7)) * 8;
        short8 vf = *(const short8*)&Vts[(dt * 16 + l16) * 64 + scol];
        oacc[0][dt] = __builtin_amdgcn_mfma_f32_16x16x32_bf16(pf[0], vf, oacc[0][dt], 0, 0, 0);
        oacc[1][dt] = __builtin_amdgcn_mfma_f32_16x16x32_bf16(pf[1], vf, oacc[1][dt], 0, 0, 0);
      }
      oaccL[0] = __builtin_amdgcn_mfma_f32_16x16x32_bf16(pf[0], ones, oaccL[0], 0, 0, 0);
      oaccL[1] = __builtin_amdgcn_mfma_f32_16x16x32_bf16(pf[1], ones, oaccL[1], 0, 0, 0);
    }
    __builtin_amdgcn_s_setprio(0);
  }

#pragma unroll
  for (int i = 0; i < 2; i++)
#pragma unroll
    for (int r = 0; r < 4; r++) {
      const float ls = __shfl(oaccL[i][r], lane & 48, 64);
      const float inv = 1.0f / ls;
      const int row = wave * 32 + i * 16 + quad * 4 + r;
#pragma unroll
      for (int dt = 0; dt < 4; dt++)
        op[(size_t)row * E_DIM + dt * 16 + l16] = f2bf(oacc[i][dt][r] * inv);
    }
}

extern "C" void kernel_launch(void* const* d_in, const int* in_sizes, int n_in,
                              void* d_out, int out_size, void* d_ws, size_t ws_size,
                              hipStream_t stream) {
  const float* Q  = (const float*)d_in[0];
  const float* K  = (const float*)d_in[1];
  const float* V  = (const float*)d_in[2];
  const float* Wq = (const float*)d_in[3];
  const float* Wk = (const float*)d_in[4];
  const float* Wv = (const float*)d_in[5];
  const float* Wo = (const float*)d_in[6];
  const float* bo = (const float*)d_in[7];
  float* out = (float*)d_out;

  char* ws = (char*)d_ws;
  const size_t wsz = (size_t)E_DIM * E_DIM * 2;   // 2MB per bf16 weight
  short* wqb = (short*)ws; ws += wsz;
  short* wkb = (short*)ws; ws += wsz;
  short* wvb = (short*)ws; ws += wsz;
  short* wob = (short*)ws; ws += wsz;
  const size_t asz = (size_t)M_TOT * E_DIM * 2;   // 16MB per activation
  _Float16* qw = (_Float16*)ws; ws += asz;
  _Float16* kw = (_Float16*)ws; ws += asz;
  short* vtw = (short*)ws;      ws += asz;        // bf16 [E, M]
  short* aw  = (short*)ws;      ws += asz;        // bf16 [M, E]
  // bf16 activation scratch, dead before final consumers: qbf -> aw (flash
  // writes aw later); kbf, vbf -> d_out (final GEMM writes out last).
  short* qbf = aw;
  short* kbf = (short*)d_out;
  short* vbf = (short*)d_out + (size_t)M_TOT * E_DIM;

  dim3 blk(256);
  cvt_w4<<<dim3(E_DIM * E_DIM / 4 / 256, 4), blk, 0, stream>>>(
      Wq, Wk, Wv, Wo, wqb, wkb, wvb, wob);
  cvt_a3<<<dim3(M_TOT * E_DIM / 4 / 256, 3), blk, 0, stream>>>(
      Q, K, V, qbf, kbf, vbf);

  gemm_k<0><<<dim3(8, 64, 3), blk, 0, stream>>>(
      qbf, kbf, vbf, wqb, wkb, wvb, qw, kw, vtw, nullptr);
  flash_attn<<<dim3(S_LEN / 128, H_NUM, B_NUM), blk, 0, stream>>>(qw, kw, vtw, aw);
  gemm_k<2><<<dim3(8, 64, 1), blk, 0, stream>>>(
      aw, nullptr, nullptr, wob, nullptr, nullptr, out, nullptr, nullptr, bo);
}

// Round 9
// 321.375 us; speedup vs baseline: 1.0630x; 1.0501x over previous
//
#include <hip/hip_runtime.h>
#include <hip/hip_bf16.h>

// Round 12: flash counted-vmcnt pipeline (T4). Round-8 evidence: 4 blocks/CU
// co-resident but pipes still ~75% summed -- the 3 __syncthreads/kt each
// drain vmcnt(0), exposing K/V staging latency 32x per block. Fix: de-alias
// Ps from Ks (LDS 26624->34816, still 4 blocks/CU) so Ks can be overwritten
// mid-iter; stage K(t+1) after QK(t), V(t) at top; raw s_barrier + vmcnt(2)
// gates (K-wait before QK, V-wait before PV) -- loads never drain to 0 in
// steady state. Numerics bitwise unchanged. GEMMs/cvts byte-identical to
// round 8 (single-variable round).

using bf16 = __hip_bfloat16;
typedef __attribute__((ext_vector_type(8))) short short8;
typedef __attribute__((ext_vector_type(4))) short short4v;
typedef _Float16 half8 __attribute__((ext_vector_type(8)));
typedef __attribute__((ext_vector_type(4))) float floatx4;

#define E_DIM 1024
#define H_NUM 16
#define D_DIM 64
#define B_NUM 4
#define S_LEN 2048
#define M_TOT 8192  // B*S

__device__ __forceinline__ void async_ld16(const void* g, void* l) {
  __builtin_amdgcn_global_load_lds(
      (const __attribute__((address_space(1))) unsigned int*)g,
      (__attribute__((address_space(3))) unsigned int*)l, 16, 0, 0);
}

// fp32 -> bf16 round-to-nearest-even (explicit; ROCm cast rounding is
// version-dependent). Inputs finite.
__device__ __forceinline__ short f2bf(float x) {
  unsigned u = __builtin_bit_cast(unsigned, x);
  u += 0x7FFFu + ((u >> 16) & 1u);
  return (short)(u >> 16);
}

// 4 weight matrices in one dispatch. grid (E*E/4/256, 4).
__global__ void cvt_w4(const float* __restrict__ a, const float* __restrict__ b,
                       const float* __restrict__ c, const float* __restrict__ d,
                       short* __restrict__ oa, short* __restrict__ ob,
                       short* __restrict__ oc, short* __restrict__ od) {
  const int z = blockIdx.y;
  const float* src = z == 0 ? a : z == 1 ? b : z == 2 ? c : d;
  short* dst = z == 0 ? oa : z == 1 ? ob : z == 2 ? oc : od;
  const int i = blockIdx.x * blockDim.x + threadIdx.x;
  float4 v = ((const float4*)src)[i];
  short4v o;
  o[0] = f2bf(v.x); o[1] = f2bf(v.y); o[2] = f2bf(v.z); o[3] = f2bf(v.w);
  ((short4v*)dst)[i] = o;
}

// Q,K,V activations in one dispatch. grid (M*E/4/256, 3).
__global__ void cvt_a3(const float* __restrict__ a, const float* __restrict__ b,
                       const float* __restrict__ c, short* __restrict__ oa,
                       short* __restrict__ ob, short* __restrict__ oc) {
  const int z = blockIdx.y;
  const float* src = z == 0 ? a : z == 1 ? b : c;
  short* dst = z == 0 ? oa : z == 1 ? ob : oc;
  const int i = blockIdx.x * blockDim.x + threadIdx.x;
  float4 v = ((const float4*)src)[i];
  short4v o;
  o[0] = f2bf(v.x); o[1] = f2bf(v.y); o[2] = f2bf(v.z); o[3] = f2bf(v.w);
  ((short4v*)dst)[i] = o;
}

// C = A @ W^T, A bf16 [M,K], W bf16 [N,K], both via global_load_lds with
// XOR-swizzled LDS (BK=64).  (Round-3 version -- best measured.)
// MODE 0: QKV batch, grid (8,64,3). z=0/1 -> f16 [M,N]; z=2 -> bf16 [N,M]
//         via LDS-restaged coalesced short8 stores.
// MODE 2: single, grid (8,64,1), f32 [M,N] + bias.
template <int MODE>
__global__ __launch_bounds__(256, 3) void gemm_k(
    const short* __restrict__ A0, const short* __restrict__ A1,
    const short* __restrict__ A2, const short* __restrict__ W0,
    const short* __restrict__ W1, const short* __restrict__ W2,
    void* __restrict__ C0, void* __restrict__ C1p, void* __restrict__ C2p,
    const float* __restrict__ bias) {
  __shared__ __align__(16) char smem[MODE == 0 ? 34816 : 32768];
  short* As = (short*)smem;            // bf16 [128][64] swizzled
  short* Ws = (short*)(smem + 16384);  // bf16 [128][64] swizzled
  short* Cs = (short*)smem;            // bf16 [128][136] (z==2 epilogue only)

  const int M = M_TOT, N = E_DIM, K = E_DIM;
  const int tid = threadIdx.x;
  const int wave = tid >> 6;
  const int lane = tid & 63;
  const int quad = lane >> 4;
  const int l16 = lane & 15;
  const int wr = wave >> 1, wc = wave & 1;

  const int z = (MODE == 0) ? blockIdx.z : 0;
  const short* A = (MODE == 0) ? (z == 0 ? A0 : z == 1 ? A1 : A2) : A0;
  const short* W = (MODE == 0) ? (z == 0 ? W0 : z == 1 ? W1 : W2) : W0;

  const int nBase = (blockIdx.y & 7) * 128;
  const int mBase = (blockIdx.x * 8 + (blockIdx.y >> 3)) * 128;

  // Staging source swizzle: dest slot s=lane&7 of row r holds global
  // col-group s ^ (r&7); read side applies same XOR (both-sides rule).
  const int sRow = lane >> 3;
  const int sSwz = ((lane & 7) ^ sRow) * 8;
  const int rdSwz0 = ((0 * 4 + quad) ^ (l16 & 7)) * 8;
  const int rdSwz1 = ((1 * 4 + quad) ^ (l16 & 7)) * 8;

  floatx4 acc[4][4] = {};

  for (int kb = 0; kb < K; kb += 64) {
    __syncthreads();
#pragma unroll
    for (int t = 0; t < 4; t++) {
      const int r0 = wave * 32 + t * 8;
      async_ld16(&W[(size_t)(nBase + r0 + sRow) * K + kb + sSwz], &Ws[r0 * 64]);
      async_ld16(&A[(size_t)(mBase + r0 + sRow) * K + kb + sSwz], &As[r0 * 64]);
    }
    __syncthreads();
#pragma unroll
    for (int ks = 0; ks < 2; ks++) {
      const int rs = ks ? rdSwz1 : rdSwz0;
      short8 af[4], wf[4];
#pragma unroll
      for (int i = 0; i < 4; i++)
        af[i] = *(const short8*)&As[(wr * 64 + i * 16 + l16) * 64 + rs];
#pragma unroll
      for (int j = 0; j < 4; j++)
        wf[j] = *(const short8*)&Ws[(wc * 64 + j * 16 + l16) * 64 + rs];
#pragma unroll
      for (int i = 0; i < 4; i++)
#pragma unroll
        for (int j = 0; j < 4; j++)
          acc[i][j] = __builtin_amdgcn_mfma_f32_16x16x32_bf16(af[i], wf[j], acc[i][j], 0, 0, 0);
    }
  }

  if (MODE == 2) {
#pragma unroll
    for (int i = 0; i < 4; i++) {
      const int row0 = mBase + wr * 64 + i * 16 + quad * 4;
#pragma unroll
      for (int j = 0; j < 4; j++) {
        const int col = nBase + wc * 64 + j * 16 + l16;
        const float bv = bias[col];
#pragma unroll
        for (int r = 0; r < 4; r++)
          ((float*)C0)[(size_t)(row0 + r) * N + col] = acc[i][j][r] + bv;
      }
    }
  } else if (z != 2) {
    _Float16* C = (_Float16*)(z == 0 ? C0 : C1p);
#pragma unroll
    for (int i = 0; i < 4; i++) {
      const int row0 = mBase + wr * 64 + i * 16 + quad * 4;
#pragma unroll
      for (int j = 0; j < 4; j++) {
        const int col = nBase + wc * 64 + j * 16 + l16;
#pragma unroll
        for (int r = 0; r < 4; r++)
          C[(size_t)(row0 + r) * N + col] = (_Float16)acc[i][j][r];
      }
    }
  } else {
    // bf16 [N,M]: restage through LDS, store coalesced short8 rows of C^T.
    __syncthreads();  // all LDS fragment reads done before Cs overwrites
#pragma unroll
    for (int i = 0; i < 4; i++) {
      const int rl = wr * 64 + i * 16 + quad * 4;
#pragma unroll
      for (int j = 0; j < 4; j++) {
        const int cl = wc * 64 + j * 16 + l16;
#pragma unroll
        for (int r = 0; r < 4; r++)
          Cs[cl * 136 + rl + r] = f2bf(acc[i][j][r]);
      }
    }
    __syncthreads();
    short* C = (short*)C2p;
#pragma unroll
    for (int p = 0; p < 8; p++) {
      const int id = p * 256 + tid;
      const int nl = id >> 4, mc = (id & 15) * 8;
      *(short8*)&C[(size_t)(nBase + nl) * M + mBase + mc] =
          *(const short8*)&Cs[nl * 136 + mc];
    }
  }
}

// Flash attention v2. q,k: f16 [M,E]; vt: bf16 [E,M]; o: bf16 [M,E].
// Softmax over UNSCALED scores (reference bug preserved), shift-by-40;
// rowsum via ones-MFMA; T1 swizzle + T5 setprio.
// Round 12: KVBLK=64; Ps disjoint from Ks; counted-vmcnt K/V pipeline.
__global__ __launch_bounds__(256, 4) void flash_attn(
    const _Float16* __restrict__ q, const _Float16* __restrict__ k,
    const short* __restrict__ vt, short* __restrict__ o) {
  __shared__ __align__(16) char smem[34816];
  short* Vts = (short*)smem;                    // bf16 [64 d][64 kv] swz, 8KB
  _Float16* Ks = (_Float16*)(smem + 8192);      // f16 [64 kv][64 d] swz, 8KB
  // Ps DISJOINT (so Ks can be re-staged mid-iteration): per-wave [32][72]
  short* PsW = (short*)(smem + 16384 + (threadIdx.x >> 6) * 4608);

  const int tid = threadIdx.x;
  const int wave = tid >> 6;
  const int lane = tid & 63;
  const int quad = lane >> 4;
  const int l16 = lane & 15;

  int qRow0, h, b;
  {
    int l = blockIdx.x + ((blockIdx.y + (blockIdx.z << 4)) << 4);
    l = (l & 7) * 128 + (l >> 3);               // nwg=1024, bijective
    qRow0 = (l & 15) * 128;
    h = (l >> 4) & 15;
    b = l >> 8;
  }

  const _Float16* qp = q + (size_t)(b * S_LEN + qRow0) * E_DIM + h * D_DIM;
  const _Float16* kp = k + (size_t)(b * S_LEN) * E_DIM + h * D_DIM;
  const short* vtp = vt + (size_t)(h * D_DIM) * M_TOT + b * S_LEN;
  short* op = o + (size_t)(b * S_LEN + qRow0) * E_DIM + h * D_DIM;

  half8 qf[2][2];
#pragma unroll
  for (int i = 0; i < 2; i++)
#pragma unroll
    for (int ks = 0; ks < 2; ks++)
      qf[i][ks] = *(const half8*)&qp[(size_t)(wave * 32 + i * 16 + l16) * E_DIM + ks * 32 + quad * 8];

  short8 ones;
#pragma unroll
  for (int j = 0; j < 8; j++) ones[j] = (l16 == 0) ? (short)0x3F80 : (short)0;

  floatx4 oacc[2][4] = {};
  floatx4 oaccL[2] = {};

  // Staging: 128-B rows (8 x 16B chunks); lane L -> row r0 + (L>>3),
  // slot L&7; slot s of row r holds global chunk s ^ (r&7) (r0 % 8 == 0).
  const int sRow = lane >> 3;
  const int sSwz = ((lane & 7) ^ sRow) * 8;

  // 2 loads/thread each. Per-wave FIFO: vmcnt counts this wave's loads.
  auto stageK = [&](int t) {
#pragma unroll
    for (int tt = 0; tt < 2; tt++) {
      const int r0 = wave * 16 + tt * 8;
      async_ld16(&kp[(size_t)(t * 64 + r0 + sRow) * E_DIM + sSwz], &Ks[r0 * 64]);
    }
  };
  auto stageV = [&](int t) {
#pragma unroll
    for (int tt = 0; tt < 2; tt++) {
      const int r0 = wave * 16 + tt * 8;
      async_ld16(&vtp[(size_t)(r0 + sRow) * M_TOT + t * 64 + sSwz], &Vts[r0 * 64]);
    }
  };

  stageK(0);  // prologue; outstanding at loop top: K(kt) x2

  for (int kt = 0; kt < 32; kt++) {
    __builtin_amdgcn_s_barrier();              // (A) PV(kt-1) Vts/Ps reads done
    stageV(kt);                                // outstanding: K(kt)2 + V(kt)2
    // wait K(kt) (2 oldest); V stays in flight under QK + P-write
    asm volatile("s_waitcnt vmcnt(2)" ::: "memory");
    __builtin_amdgcn_s_barrier();              // (B) Ks visible to all waves

    floatx4 sc[2][4] = {};
    __builtin_amdgcn_s_setprio(1);
#pragma unroll
    for (int jt = 0; jt < 4; jt++) {
#pragma unroll
      for (int ks = 0; ks < 2; ks++) {
        const int scol = ((ks * 4 + quad) ^ (l16 & 7)) * 8;
        half8 kf = *(const half8*)&Ks[(jt * 16 + l16) * 64 + scol];
        sc[0][jt] = __builtin_amdgcn_mfma_f32_16x16x32_f16(qf[0][ks], kf, sc[0][jt], 0, 0, 0);
        sc[1][jt] = __builtin_amdgcn_mfma_f32_16x16x32_f16(qf[1][ks], kf, sc[1][jt], 0, 0, 0);
      }
    }
    __builtin_amdgcn_s_setprio(0);
    __builtin_amdgcn_s_barrier();              // (C) all Ks reads done
    if (kt + 1 < 32) stageK(kt + 1);           // overwrite Ks; hides under
                                               // P-write + PV + barrier (A)

    // p = exp(s - 40); shift-invariant, 40 keeps exp in range. Quantize
    // p (>0) round-half-up (u+0x8000)>>16 (ties only vs RNE; num/denom
    // consistent). Ps disjoint from Ks -- no conflict with stageK above.
#pragma unroll
    for (int i = 0; i < 2; i++)
#pragma unroll
      for (int r = 0; r < 4; r++) {
        const int prow = i * 16 + quad * 4 + r;
#pragma unroll
        for (int jt = 0; jt < 4; jt++) {
          const float p = __expf(sc[i][jt][r] - 40.0f);
          const unsigned u = __builtin_bit_cast(unsigned, p);
          PsW[prow * 72 + jt * 16 + l16] = (short)((u + 0x8000u) >> 16);
        }
      }

    // wait V(kt) (2 oldest; K(kt+1) stays in flight), then make Vts visible
    if (kt + 1 < 32) asm volatile("s_waitcnt vmcnt(2)" ::: "memory");
    else             asm volatile("s_waitcnt vmcnt(0)" ::: "memory");
    __builtin_amdgcn_s_barrier();              // (D) Vts staged

    __builtin_amdgcn_s_setprio(1);
#pragma unroll
    for (int ks = 0; ks < 2; ks++) {
      short8 pf[2];
#pragma unroll
      for (int i = 0; i < 2; i++)
        pf[i] = *(const short8*)&PsW[(i * 16 + l16) * 72 + ks * 32 + quad * 8];
#pragma unroll
      for (int dt = 0; dt < 4; dt++) {
        const int scol = ((ks * 4 + quad) ^ (l16 & 7)) * 8;
        short8 vf = *(const short8*)&Vts[(dt * 16 + l16) * 64 + scol];
        oacc[0][dt] = __builtin_amdgcn_mfma_f32_16x16x32_bf16(pf[0], vf, oacc[0][dt], 0, 0, 0);
        oacc[1][dt] = __builtin_amdgcn_mfma_f32_16x16x32_bf16(pf[1], vf, oacc[1][dt], 0, 0, 0);
      }
      oaccL[0] = __builtin_amdgcn_mfma_f32_16x16x32_bf16(pf[0], ones, oaccL[0], 0, 0, 0);
      oaccL[1] = __builtin_amdgcn_mfma_f32_16x16x32_bf16(pf[1], ones, oaccL[1], 0, 0, 0);
    }
    __builtin_amdgcn_s_setprio(0);
  }

#pragma unroll
  for (int i = 0; i < 2; i++)
#pragma unroll
    for (int r = 0; r < 4; r++) {
      const float ls = __shfl(oaccL[i][r], lane & 48, 64);
      const float inv = 1.0f / ls;
      const int row = wave * 32 + i * 16 + quad * 4 + r;
#pragma unroll
      for (int dt = 0; dt < 4; dt++)
        op[(size_t)row * E_DIM + dt * 16 + l16] = f2bf(oacc[i][dt][r] * inv);
    }
}

extern "C" void kernel_launch(void* const* d_in, const int* in_sizes, int n_in,
                              void* d_out, int out_size, void* d_ws, size_t ws_size,
                              hipStream_t stream) {
  const float* Q  = (const float*)d_in[0];
  const float* K  = (const float*)d_in[1];
  const float* V  = (const float*)d_in[2];
  const float* Wq = (const float*)d_in[3];
  const float* Wk = (const float*)d_in[4];
  const float* Wv = (const float*)d_in[5];
  const float* Wo = (const float*)d_in[6];
  const float* bo = (const float*)d_in[7];
  float* out = (float*)d_out;

  char* ws = (char*)d_ws;
  const size_t wsz = (size_t)E_DIM * E_DIM * 2;   // 2MB per bf16 weight
  short* wqb = (short*)ws; ws += wsz;
  short* wkb = (short*)ws; ws += wsz;
  short* wvb = (short*)ws; ws += wsz;
  short* wob = (short*)ws; ws += wsz;
  const size_t asz = (size_t)M_TOT * E_DIM * 2;   // 16MB per activation
  _Float16* qw = (_Float16*)ws; ws += asz;
  _Float16* kw = (_Float16*)ws; ws += asz;
  short* vtw = (short*)ws;      ws += asz;        // bf16 [E, M]
  short* aw  = (short*)ws;      ws += asz;        // bf16 [M, E]
  // bf16 activation scratch, dead before final consumers: qbf -> aw (flash
  // writes aw later); kbf, vbf -> d_out (final GEMM writes out last).
  short* qbf = aw;
  short* kbf = (short*)d_out;
  short* vbf = (short*)d_out + (size_t)M_TOT * E_DIM;

  dim3 blk(256);
  cvt_w4<<<dim3(E_DIM * E_DIM / 4 / 256, 4), blk, 0, stream>>>(
      Wq, Wk, Wv, Wo, wqb, wkb, wvb, wob);
  cvt_a3<<<dim3(M_TOT * E_DIM / 4 / 256, 3), blk, 0, stream>>>(
      Q, K, V, qbf, kbf, vbf);

  gemm_k<0><<<dim3(8, 64, 3), blk, 0, stream>>>(
      qbf, kbf, vbf, wqb, wkb, wvb, qw, kw, vtw, nullptr);
  flash_attn<<<dim3(S_LEN / 128, H_NUM, B_NUM), blk, 0, stream>>>(qw, kw, vtw, aw);
  gemm_k<2><<<dim3(8, 64, 1), blk, 0, stream>>>(
      aw, nullptr, nullptr, wob, nullptr, nullptr, out, nullptr, nullptr, bo);
}